// Round 3
// baseline (857.907 us; speedup 1.0000x reference)
//
#include <hip/hip_runtime.h>
#include <math.h>

#define NI 128
#define NC 256
#define NR 36
#define NW 48
#define ND 256

#define PIB 264      // sIb / sCb pitch (bf16): 528 B rows, 16B-aligned, 2-way banks
#define PT  56       // sIT pitch: 112 B rows, 16B-aligned, 2-way banks
#define PP  72       // sP pitch: 144 B rows, 16B-aligned, 2-way banks

typedef __bf16 bf16;
typedef __bf16 bf16x8 __attribute__((ext_vector_type(8)));
typedef __bf16 bf16x4 __attribute__((ext_vector_type(4)));
typedef float  f32x4  __attribute__((ext_vector_type(4)));

// LDS carve (bytes)
#define OFF_IB   0            // 36*264*2  = 19008
#define OFF_IT   19008        // 256*56*2  = 28672 -> 47680
#define OFF_CB   47680        // 48*264*2  = 25344 -> 73024
#define OFF_P    73024        // 48*72*2   = 6912  -> 79936
#define OFF_W1   79936        // 48*4 -> 80128
#define OFF_W12  80128        // -> 80320
#define OFF_W2   80320        // -> 80512
#define OFF_SSQ  80512        // -> 80704
#define SMEM_TOTAL 80704      // 78.8 KB -> 2 blocks/CU

__global__ __launch_bounds__(512, 4)
void scan_kernel(const float* __restrict__ images,
                 const float* __restrict__ captions,
                 float* __restrict__ out)
{
    __shared__ __align__(16) unsigned char smem[SMEM_TOTAL];
    bf16*  sIb  = (bf16*)(smem + OFF_IB);   // [r][d]   image rows (phase-1 B)
    bf16*  sIT  = (bf16*)(smem + OFF_IT);   // [d][r]   image^T (phase-2 B)
    bf16*  sCb  = (bf16*)(smem + OFF_CB);   // [w][d]   caption (phase-1 A + epilogue)
    bf16*  sP   = (bf16*)(smem + OFF_P);    // [w][r]   softmax probs, r>=36 zero
    float* w1s  = (float*)(smem + OFF_W1);
    float* w12s = (float*)(smem + OFF_W12);
    float* w2s  = (float*)(smem + OFF_W2);
    float* ssq  = (float*)(smem + OFF_SSQ);

    const int tid  = threadIdx.x;
    const int wave = tid >> 6;
    const int lane = tid & 63;
    const int quad = lane >> 4;
    const int l15  = lane & 15;
    const int i      = blockIdx.x >> 2;          // 128 images x 4 caption chunks
    const int c_base = (blockIdx.x & 3) * 64;

    const float* gI = images + (size_t)i * NR * ND;

    // ---- once per block: stage image [r][d] ----
    #pragma unroll
    for (int k = 0; k < 5; ++k) {
        int t = tid + k * 512;
        if (t < 2304) {                          // 36*256/4 float4
            int e = t * 4, r = e >> 8, d = e & 255;
            float4 v = *(const float4*)(gI + e);
            bf16x4 h = { (bf16)v.x, (bf16)v.y, (bf16)v.z, (bf16)v.w };
            *(bf16x4*)&sIb[r * PIB + d] = h;
        }
    }
    // ---- once per block: build image^T [d][r], r>=36 zeroed ----
    #pragma unroll
    for (int k = 0; k < 6; ++k) {
        int t = tid + k * 512;                   // 3072 = 256 d * 12 r-quads
        int d = t & 255, r0 = (t >> 8) * 4;      // r0 in {0,4,...,44}
        bf16x4 h = { (bf16)0.f, (bf16)0.f, (bf16)0.f, (bf16)0.f };
        if (r0 < NR) {
            h.x = (bf16)gI[(r0 + 0) * ND + d];
            h.y = (bf16)gI[(r0 + 1) * ND + d];
            h.z = (bf16)gI[(r0 + 2) * ND + d];
            h.w = (bf16)gI[(r0 + 3) * ND + d];
        }
        *(bf16x4*)&sIT[d * PT + r0] = h;
    }
    // ---- once: zero sP[w][48..63] (A-operand k-pad), w12s/w2s/ssq ----
    if (tid < 192) {
        int w = tid >> 2, j = tid & 3;
        bf16x4 z = { (bf16)0.f, (bf16)0.f, (bf16)0.f, (bf16)0.f };
        *(bf16x4*)&sP[w * PP + 48 + j * 4] = z;
    }
    if (tid < NW) { w12s[tid] = 0.f; w2s[tid] = 0.f; ssq[tid] = 0.f; }
    __syncthreads();

    for (int it = 0; it < 64; ++it) {
        const int c = c_base + it;
        const float* gC = captions + (size_t)c * NW * ND;

        // ---- stage caption -> sCb bf16; fp32 row norms -> w1s ----
        #pragma unroll
        for (int k = 0; k < 6; ++k) {
            int w = k * 8 + wave;                // one caption row per (step,wave)
            int d = lane * 4;
            float4 v = *(const float4*)(gC + w * ND + d);
            bf16x4 h = { (bf16)v.x, (bf16)v.y, (bf16)v.z, (bf16)v.w };
            *(bf16x4*)&sCb[w * PIB + d] = h;
            float s = v.x*v.x + v.y*v.y + v.z*v.z + v.w*v.w;
            s += __shfl_xor(s, 1);  s += __shfl_xor(s, 2);  s += __shfl_xor(s, 4);
            s += __shfl_xor(s, 8);  s += __shfl_xor(s, 16); s += __shfl_xor(s, 32);
            if (lane == 0) w1s[w] = sqrtf(s);
        }
        __syncthreads();   // B1: sCb/w1s ready; prev iter fully done

        // ---- phase 1 (waves 0-2): attnT[w][r] = leaky(C·I^T), reg-resident ----
        float x[3][4];     // [nt][p]: value at w = wave*16+quad*4+p, r = nt*16+l15
        if (wave < 3) {
            f32x4 acc0 = {0,0,0,0}, acc1 = {0,0,0,0}, acc2 = {0,0,0,0};
            const bf16* arow = &sCb[(wave * 16 + l15) * PIB + quad * 8];
            const bf16* brow = &sIb[l15 * PIB + quad * 8];
            #pragma unroll
            for (int k0 = 0; k0 < ND; k0 += 32) {
                bf16x8 a  = *(const bf16x8*)(arow + k0);
                bf16x8 b0 = *(const bf16x8*)(brow + k0);
                bf16x8 b1 = *(const bf16x8*)(brow + 16 * PIB + k0);
                bf16x8 b2 = *(const bf16x8*)(brow + 32 * PIB + k0);  // rows>=36 spill: masked later
                acc0 = __builtin_amdgcn_mfma_f32_16x16x32_bf16(a, b0, acc0, 0, 0, 0);
                acc1 = __builtin_amdgcn_mfma_f32_16x16x32_bf16(a, b1, acc1, 0, 0, 0);
                acc2 = __builtin_amdgcn_mfma_f32_16x16x32_bf16(a, b2, acc2, 0, 0, 0);
            }
            float part0 = 0.f, part1 = 0.f, part2 = 0.f;
            #pragma unroll
            for (int p = 0; p < 4; ++p) {
                float t0 = acc0[p]; t0 = t0 > 0.f ? t0 : 0.1f * t0; x[0][p] = t0; part0 += t0 * t0;
                float t1 = acc1[p]; t1 = t1 > 0.f ? t1 : 0.1f * t1; x[1][p] = t1; part1 += t1 * t1;
                float t2 = acc2[p]; t2 = t2 > 0.f ? t2 : 0.1f * t2; x[2][p] = t2; part2 += t2 * t2;
            }
            // sum over w (quads) -- xor 16/32 stays within same l15 (r)
            part0 += __shfl_xor(part0, 16); part0 += __shfl_xor(part0, 32);
            part1 += __shfl_xor(part1, 16); part1 += __shfl_xor(part1, 32);
            part2 += __shfl_xor(part2, 16); part2 += __shfl_xor(part2, 32);
            if (quad == 0) {
                atomicAdd(&ssq[l15], part0);
                atomicAdd(&ssq[16 + l15], part1);
                if (l15 < 4) atomicAdd(&ssq[32 + l15], part2);   // r<36 only
            }
        }
        __syncthreads();   // B2: ssq complete

        // ---- softmax over r per w (waves 0-2, registers) -> sP bf16 ----
        if (wave < 3) {
            float inv0 = 1.f / (sqrtf(ssq[l15]) + 1e-8f);
            float inv1 = 1.f / (sqrtf(ssq[16 + l15]) + 1e-8f);
            float inv2 = (l15 < 4) ? 1.f / (sqrtf(ssq[32 + l15]) + 1e-8f) : 0.f;
            #pragma unroll
            for (int p = 0; p < 4; ++p) {
                float x0 = x[0][p] * inv0 * 9.0f;
                float x1 = x[1][p] * inv1 * 9.0f;
                float x2 = (l15 < 4) ? x[2][p] * inv2 * 9.0f : -1e30f;  // mask r>=36 (garbage)
                float m = fmaxf(fmaxf(x0, x1), x2);
                m = fmaxf(m, __shfl_xor(m, 1)); m = fmaxf(m, __shfl_xor(m, 2));
                m = fmaxf(m, __shfl_xor(m, 4)); m = fmaxf(m, __shfl_xor(m, 8));
                float e0 = __expf(x0 - m), e1 = __expf(x1 - m);
                float e2 = (l15 < 4) ? __expf(x2 - m) : 0.f;
                float s = e0 + e1 + e2;
                s += __shfl_xor(s, 1); s += __shfl_xor(s, 2);
                s += __shfl_xor(s, 4); s += __shfl_xor(s, 8);
                float is = 1.f / s;
                int w = wave * 16 + quad * 4 + p;
                sP[w * PP + l15]      = (bf16)(e0 * is);
                sP[w * PP + 16 + l15] = (bf16)(e1 * is);
                sP[w * PP + 32 + l15] = (bf16)(e2 * is);   // zeros for r>=36
            }
        }
        __syncthreads();   // B3: sP complete

        // ---- phase 2 (all 8 waves): wctx = P·I (K=64, zeros in A) + cosine partials ----
        {
            const int d0 = wave * 16 + l15;
            const int d1 = d0 + 128;
            const bf16* bp0 = &sIT[d0 * PT];
            const bf16* bp1 = &sIT[d1 * PT];
            bf16x8 b0a = *(const bf16x8*)(bp0 + quad * 8);
            bf16x8 b0b = *(const bf16x8*)(bp0 + 32 + quad * 8);   // k>=48 spills: A is zero there
            bf16x8 b1a = *(const bf16x8*)(bp1 + quad * 8);
            bf16x8 b1b = *(const bf16x8*)(bp1 + 32 + quad * 8);
            float p12[3][4], p2[3][4];
            #pragma unroll
            for (int mt = 0; mt < 3; ++mt) {
                const bf16* ap = &sP[(mt * 16 + l15) * PP];
                bf16x8 aa = *(const bf16x8*)(ap + quad * 8);
                bf16x8 ab = *(const bf16x8*)(ap + 32 + quad * 8);
                f32x4 accA = {0,0,0,0}, accB = {0,0,0,0};
                accA = __builtin_amdgcn_mfma_f32_16x16x32_bf16(aa, b0a, accA, 0, 0, 0);
                accA = __builtin_amdgcn_mfma_f32_16x16x32_bf16(ab, b0b, accA, 0, 0, 0);
                accB = __builtin_amdgcn_mfma_f32_16x16x32_bf16(aa, b1a, accB, 0, 0, 0);
                accB = __builtin_amdgcn_mfma_f32_16x16x32_bf16(ab, b1b, accB, 0, 0, 0);
                #pragma unroll
                for (int p = 0; p < 4; ++p) {
                    int w = mt * 16 + quad * 4 + p;
                    float vA = accA[p], vB = accB[p];
                    float cA = (float)sCb[w * PIB + d0];
                    float cB = (float)sCb[w * PIB + d1];
                    p12[mt][p] = cA * vA + cB * vB;
                    p2 [mt][p] = vA * vA + vB * vB;
                }
            }
            #pragma unroll
            for (int mt = 0; mt < 3; ++mt) {
                #pragma unroll
                for (int p = 0; p < 4; ++p) {
                    float a = p12[mt][p], b = p2[mt][p];
                    a += __shfl_xor(a, 1); a += __shfl_xor(a, 2);
                    a += __shfl_xor(a, 4); a += __shfl_xor(a, 8);
                    b += __shfl_xor(b, 1); b += __shfl_xor(b, 2);
                    b += __shfl_xor(b, 4); b += __shfl_xor(b, 8);
                    if (l15 == 0) {
                        int w = mt * 16 + quad * 4 + p;
                        atomicAdd(&w12s[w], a);
                        atomicAdd(&w2s[w], b);
                    }
                }
            }
        }
        float w1v = 0.f;
        if (wave == 0 && lane < NW) w1v = w1s[lane];          // preload before next staging
        if (wave == 3 && lane < NW) ssq[lane] = 0.f;          // reset for next iter
        __syncthreads();   // B4: phase-2 atomics complete

        // ---- wave 0: row_sim + LSE + store; others proceed to next staging ----
        if (wave == 0) {
            float v = -1e30f;
            if (lane < NW) {
                float w2v = sqrtf(w2s[lane]);
                float rsim = w12s[lane] / fmaxf(w1v * w2v, 1e-8f);
                v = 6.0f * rsim;
                w12s[lane] = 0.f; w2s[lane] = 0.f;            // reset for next iter
            }
            float m = v;
            m = fmaxf(m, __shfl_xor(m, 1));  m = fmaxf(m, __shfl_xor(m, 2));
            m = fmaxf(m, __shfl_xor(m, 4));  m = fmaxf(m, __shfl_xor(m, 8));
            m = fmaxf(m, __shfl_xor(m, 16)); m = fmaxf(m, __shfl_xor(m, 32));
            float e = (lane < NW) ? __expf(v - m) : 0.f;
            e += __shfl_xor(e, 1);  e += __shfl_xor(e, 2);  e += __shfl_xor(e, 4);
            e += __shfl_xor(e, 8);  e += __shfl_xor(e, 16); e += __shfl_xor(e, 32);
            if (lane == 0) out[(size_t)i * NC + c] = (m + logf(e)) / 6.0f;
        }
    }
}

extern "C" void kernel_launch(void* const* d_in, const int* in_sizes, int n_in,
                              void* d_out, int out_size, void* d_ws, size_t ws_size,
                              hipStream_t stream) {
    const float* images   = (const float*)d_in[0];   // (128, 36, 256) fp32
    const float* captions = (const float*)d_in[1];   // (256, 48, 256) fp32
    float* out = (float*)d_out;                      // (128, 256) fp32

    dim3 grid(512);      // 128 images x 4 caption chunks; 2 blocks/CU
    dim3 block(512);
    hipLaunchKernelGGL(scan_kernel, grid, block, 0, stream, images, captions, out);
}

// Round 5
// 433.974 us; speedup vs baseline: 1.9769x; 1.9769x over previous
//
#include <hip/hip_runtime.h>
#include <math.h>

#define NI 128
#define NC 256
#define NR 36
#define NW 48
#define ND 256

#define PCB 264      // sCb/sIb pitch (bf16): 528 B rows
#define PG  72       // sG pitch (bf16): 144 B rows
#define PP  72       // sP pitch (bf16): 144 B rows

typedef __bf16 bf16;
typedef __bf16 bf16x8 __attribute__((ext_vector_type(8)));
typedef __bf16 bf16x4 __attribute__((ext_vector_type(4)));
typedef float  f32x4  __attribute__((ext_vector_type(4)));

// LDS carve (bytes)
#define OFF_CB  0        // 48*264*2 = 25344 (sIb overlaid here during init)
#define OFF_G   25344    // 48*72*2  = 6912 -> 32256
#define OFF_P   32256    // 48*72*2  = 6912 -> 39168
#define OFF_RS  39168    // 48*4 -> 39360
#define OFF_SSQ 39360    // 48*4 -> 39552
#define OFF_W1  39552    // 48*4 -> 39744
#define SMEM_TOTAL 39744 // 38.8 KB

// ---- 16-lane (DPP-row) reductions on the VALU pipe (no DS traffic) ----
__device__ __forceinline__ float dpp_add16(float v) {
    int x = __builtin_bit_cast(int, v);
    v += __builtin_bit_cast(float, __builtin_amdgcn_update_dpp(0, x, 0xB1, 0xF, 0xF, true));   // quad_perm(1,0,3,2)
    x = __builtin_bit_cast(int, v);
    v += __builtin_bit_cast(float, __builtin_amdgcn_update_dpp(0, x, 0x4E, 0xF, 0xF, true));   // quad_perm(2,3,0,1)
    x = __builtin_bit_cast(int, v);
    v += __builtin_bit_cast(float, __builtin_amdgcn_update_dpp(0, x, 0x141, 0xF, 0xF, true));  // row_half_mirror
    x = __builtin_bit_cast(int, v);
    v += __builtin_bit_cast(float, __builtin_amdgcn_update_dpp(0, x, 0x140, 0xF, 0xF, true));  // row_mirror
    return v;   // all 16 lanes of the row hold the sum
}
__device__ __forceinline__ float dpp_max16(float v) {
    int x = __builtin_bit_cast(int, v);
    v = fmaxf(v, __builtin_bit_cast(float, __builtin_amdgcn_update_dpp(0, x, 0xB1, 0xF, 0xF, true)));
    x = __builtin_bit_cast(int, v);
    v = fmaxf(v, __builtin_bit_cast(float, __builtin_amdgcn_update_dpp(0, x, 0x4E, 0xF, 0xF, true)));
    x = __builtin_bit_cast(int, v);
    v = fmaxf(v, __builtin_bit_cast(float, __builtin_amdgcn_update_dpp(0, x, 0x141, 0xF, 0xF, true)));
    x = __builtin_bit_cast(int, v);
    v = fmaxf(v, __builtin_bit_cast(float, __builtin_amdgcn_update_dpp(0, x, 0x140, 0xF, 0xF, true)));
    return v;
}

// ---- prep: captions fp32 -> bf16 cache + per-caption-row L2 norms ----
__global__ __launch_bounds__(256)
void prep_kernel(const float* __restrict__ captions, bf16* __restrict__ capb,
                 float* __restrict__ w1g)
{
    const int c = blockIdx.x, wave = threadIdx.x >> 6, lane = threadIdx.x & 63;
    const float* src = captions + (size_t)c * NW * ND;
    #pragma unroll
    for (int j = 0; j < 12; ++j) {
        int w = wave * 12 + j;
        float4 v = *(const float4*)(src + w * ND + lane * 4);
        bf16x4 h = { (bf16)v.x, (bf16)v.y, (bf16)v.z, (bf16)v.w };
        *(bf16x4*)(capb + (size_t)c * (NW * ND) + w * ND + lane * 4) = h;
        float s = v.x*v.x + v.y*v.y + v.z*v.z + v.w*v.w;
        s += __shfl_xor(s, 1);  s += __shfl_xor(s, 2);  s += __shfl_xor(s, 4);
        s += __shfl_xor(s, 8);  s += __shfl_xor(s, 16); s += __shfl_xor(s, 32);
        if (lane == 0) w1g[c * NW + w] = sqrtf(s);
    }
}

template<bool USE_WS>
__global__ __launch_bounds__(256, 3)
void scan_main(const float* __restrict__ images,
               const float* __restrict__ captions,
               const bf16* __restrict__ capb,
               const float* __restrict__ w1g,
               float* __restrict__ out)
{
    __shared__ __align__(16) unsigned char smem[SMEM_TOTAL];
    bf16*  sCb = (bf16*)(smem + OFF_CB);    // [w][d] caption (phase-1 A); sIb overlaid at init
    bf16*  sIb = (bf16*)(smem + OFF_CB);    // [r][d] image (init only: Gram + frag preload)
    bf16*  sG  = (bf16*)(smem + OFF_G);     // [r'][r] Gram bf16; pads explicitly zeroed
    bf16*  sP  = (bf16*)(smem + OFF_P);     // [w][r] probs, k 36..63 always zero
    float* rs  = (float*)(smem + OFF_RS);
    float* ssq = (float*)(smem + OFF_SSQ);
    float* w1s = (float*)(smem + OFF_W1);   // only used when !USE_WS

    const int tid  = threadIdx.x;
    const int wave = tid >> 6;
    const int lane = tid & 63;
    const int quad = lane >> 4;
    const int l15  = lane & 15;
    const int i     = blockIdx.x >> 3;       // 128 images
    const int c0    = (blockIdx.x & 7) * 32; // chunk == blockIdx%8 -> XCD-pinned captions

    // ---- init: stage image fp32->bf16 into sIb rows 0..35 ----
    const float* gI = images + (size_t)i * NR * ND;
    #pragma unroll
    for (int k = 0; k < 9; ++k) {
        int t = tid + k * 256;               // 2304 float4
        int e = t * 4, r = e >> 8, d = e & 255;
        float4 v = *(const float4*)(gI + e);
        bf16x4 h = { (bf16)v.x, (bf16)v.y, (bf16)v.z, (bf16)v.w };
        *(bf16x4*)&sIb[r * PCB + d] = h;
    }
    // ---- ZERO all garbage-read regions (NaN/inf-through-MFMA guard; R4 bug) ----
    {
        // sIb rows 36..47: dwords 4752..6335 (1584)
        uint32_t* pIb = (uint32_t*)sIb;
        #pragma unroll
        for (int k = 0; k < 7; ++k) { int x = tid + k * 256; if (x < 1584) pIb[4752 + x] = 0u; }
        // whole sG: 3456 dwords (Gram rewrites 0..47 x 0..47; col-pad 48..71 stays 0)
        uint32_t* pG = (uint32_t*)sG;
        #pragma unroll
        for (int k = 0; k < 14; ++k) { int x = tid + k * 256; if (x < 3456) pG[x] = 0u; }
        // sP k-pad 48..63
        if (tid < 192) {
            int w = tid >> 2, j = tid & 3;
            bf16x4 z = { (bf16)0.f, (bf16)0.f, (bf16)0.f, (bf16)0.f };
            *(bf16x4*)&sP[w * PP + 48 + j * 4] = z;
        }
        if (tid < NR) ssq[tid] = 0.f;
    }
    __syncthreads();

    // ---- once per block: Gram G[r'][r] = I·I^T (bf16 out), waves 0-2 ----
    if (wave < 3) {
        f32x4 g0 = {0,0,0,0}, g1 = {0,0,0,0}, g2 = {0,0,0,0};
        #pragma unroll
        for (int ks = 0; ks < 8; ++ks) {
            bf16x8 a  = *(const bf16x8*)&sIb[(wave * 16 + l15) * PCB + ks * 32 + quad * 8];
            bf16x8 b0 = *(const bf16x8*)&sIb[(l15)            * PCB + ks * 32 + quad * 8];
            bf16x8 b1 = *(const bf16x8*)&sIb[(16 + l15)       * PCB + ks * 32 + quad * 8];
            bf16x8 b2 = *(const bf16x8*)&sIb[(32 + l15)       * PCB + ks * 32 + quad * 8];
            g0 = __builtin_amdgcn_mfma_f32_16x16x32_bf16(a, b0, g0, 0, 0, 0);
            g1 = __builtin_amdgcn_mfma_f32_16x16x32_bf16(a, b1, g1, 0, 0, 0);
            g2 = __builtin_amdgcn_mfma_f32_16x16x32_bf16(a, b2, g2, 0, 0, 0);
        }
        #pragma unroll
        for (int p = 0; p < 4; ++p) {
            int m = wave * 16 + quad * 4 + p;
            sG[m * PG + l15]      = (bf16)g0[p];
            sG[m * PG + 16 + l15] = (bf16)g1[p];
            sG[m * PG + 32 + l15] = (bf16)g2[p];
        }
    }
    // ---- once per block: preload phase-1 image B-fragments into registers (96 VGPR) ----
    bf16x8 ibf[3][8];
    if (wave < 3) {
        #pragma unroll
        for (int nt = 0; nt < 3; ++nt)
            #pragma unroll
            for (int ks = 0; ks < 8; ++ks)
                ibf[nt][ks] = *(const bf16x8*)&sIb[(nt * 16 + l15) * PCB + ks * 32 + quad * 8];
    }
    __syncthreads();   // sIb region free -> becomes sCb

    for (int it = 0; it < 32; ++it) {
        const int c = c0 + it;

        // ---- stage caption c -> sCb ----
        if (USE_WS) {
            const bf16* src = capb + (size_t)c * (NW * ND);
            #pragma unroll
            for (int j = 0; j < 12; ++j) {
                int w = wave * 12 + j;
                uint2 v = *(const uint2*)(src + w * ND + lane * 4);
                *(uint2*)&sCb[w * PCB + lane * 4] = v;
            }
        } else {
            const float* src = captions + (size_t)c * NW * ND;
            #pragma unroll
            for (int j = 0; j < 12; ++j) {
                int w = wave * 12 + j;
                float4 v = *(const float4*)(src + w * ND + lane * 4);
                bf16x4 h = { (bf16)v.x, (bf16)v.y, (bf16)v.z, (bf16)v.w };
                *(bf16x4*)&sCb[w * PCB + lane * 4] = h;
                float s = v.x*v.x + v.y*v.y + v.z*v.z + v.w*v.w;
                s += __shfl_xor(s, 1);  s += __shfl_xor(s, 2);  s += __shfl_xor(s, 4);
                s += __shfl_xor(s, 8);  s += __shfl_xor(s, 16); s += __shfl_xor(s, 32);
                if (lane == 0) w1s[w] = sqrtf(s);
            }
        }
        float w1v[4];
        if (USE_WS && wave < 3) {
            #pragma unroll
            for (int p = 0; p < 4; ++p)
                w1v[p] = w1g[(size_t)c * NW + wave * 16 + quad * 4 + p];  // latency hidden across phases
        }
        __syncthreads();   // B1: sCb ready; prev iter phase-2 done

        // ---- phase 1 (waves 0-2): raw logits + leaky + ssq over w ----
        float xr[3][4];    // post-leaky value at (w = wave*16+quad*4+p, r = nt*16+l15)
        if (wave < 3) {
            f32x4 a0 = {0,0,0,0}, a1 = {0,0,0,0}, a2 = {0,0,0,0};
            const bf16* ap = &sCb[(wave * 16 + l15) * PCB + quad * 8];
            #pragma unroll
            for (int ks = 0; ks < 8; ++ks) {
                bf16x8 a = *(const bf16x8*)(ap + ks * 32);
                a0 = __builtin_amdgcn_mfma_f32_16x16x32_bf16(a, ibf[0][ks], a0, 0, 0, 0);
                a1 = __builtin_amdgcn_mfma_f32_16x16x32_bf16(a, ibf[1][ks], a1, 0, 0, 0);
                a2 = __builtin_amdgcn_mfma_f32_16x16x32_bf16(a, ibf[2][ks], a2, 0, 0, 0);
            }
            float p0 = 0.f, p1 = 0.f, p2 = 0.f;
            #pragma unroll
            for (int p = 0; p < 4; ++p) {
                float t0 = a0[p]; t0 = t0 > 0.f ? t0 : 0.1f * t0; xr[0][p] = t0; p0 += t0 * t0;
                float t1 = a1[p]; t1 = t1 > 0.f ? t1 : 0.1f * t1; xr[1][p] = t1; p1 += t1 * t1;
                float t2 = a2[p]; t2 = t2 > 0.f ? t2 : 0.1f * t2; xr[2][p] = t2; p2 += t2 * t2;
            }
            p0 += __shfl_xor(p0, 16); p0 += __shfl_xor(p0, 32);   // sum over w-quads (crosses DPP rows)
            p1 += __shfl_xor(p1, 16); p1 += __shfl_xor(p1, 32);
            p2 += __shfl_xor(p2, 16); p2 += __shfl_xor(p2, 32);
            if (quad == 0) {
                atomicAdd(&ssq[l15], p0);
                atomicAdd(&ssq[16 + l15], p1);
                if (l15 < 4) atomicAdd(&ssq[32 + l15], p2);
            }
        }
        __syncthreads();   // B2: ssq complete

        // ---- softmax over r per w (registers + DPP); w12 = sum_r prob*raw ----
        float w12v[4];
        if (wave < 3) {
            float inv0 = 1.f / (sqrtf(ssq[l15]) + 1e-8f);
            float inv1 = 1.f / (sqrtf(ssq[16 + l15]) + 1e-8f);
            float inv2 = (l15 < 4) ? 1.f / (sqrtf(ssq[32 + l15]) + 1e-8f) : 0.f;
            #pragma unroll
            for (int p = 0; p < 4; ++p) {
                float raw0 = xr[0][p] > 0.f ? xr[0][p] : 10.f * xr[0][p];   // undo leaky
                float raw1 = xr[1][p] > 0.f ? xr[1][p] : 10.f * xr[1][p];
                float raw2 = xr[2][p] > 0.f ? xr[2][p] : 10.f * xr[2][p];
                float x0 = xr[0][p] * inv0 * 9.0f;
                float x1 = xr[1][p] * inv1 * 9.0f;
                float x2 = (l15 < 4) ? xr[2][p] * inv2 * 9.0f : -1e30f;     // mask r>=36
                float m = fmaxf(fmaxf(x0, x1), x2);
                m = dpp_max16(m);
                float e0 = __expf(x0 - m), e1 = __expf(x1 - m);
                float e2 = (l15 < 4) ? __expf(x2 - m) : 0.f;
                float s   = dpp_add16(e0 + e1 + e2);
                float num = dpp_add16(e0 * raw0 + e1 * raw1 + ((l15 < 4) ? e2 * raw2 : 0.f));
                float is = 1.f / s;
                w12v[p] = num * is;
                int w = wave * 16 + quad * 4 + p;
                sP[w * PP + l15]      = (bf16)(e0 * is);
                sP[w * PP + 16 + l15] = (bf16)(e1 * is);
                sP[w * PP + 32 + l15] = (bf16)(e2 * is);   // zeros for r>=36
            }
        }
        __syncthreads();   // B3: sP complete

        // ---- phase 2 (waves 0-2): (PG)[w][r'] then w2 = sum_r' (PG)*P via DPP ----
        if (wave < 3) {
            const bf16* ap2 = &sP[(wave * 16 + l15) * PP];
            bf16x8 pa0 = *(const bf16x8*)(ap2 + quad * 8);
            bf16x8 pa1 = *(const bf16x8*)(ap2 + 32 + quad * 8);
            f32x4 pg0 = {0,0,0,0}, pg1 = {0,0,0,0}, pg2 = {0,0,0,0};
            {
                bf16x8 b00 = *(const bf16x8*)&sG[(l15) * PG + quad * 8];
                bf16x8 b01 = *(const bf16x8*)&sG[(l15) * PG + 32 + quad * 8];
                bf16x8 b10 = *(const bf16x8*)&sG[(16 + l15) * PG + quad * 8];
                bf16x8 b11 = *(const bf16x8*)&sG[(16 + l15) * PG + 32 + quad * 8];
                bf16x8 b20 = *(const bf16x8*)&sG[(32 + l15) * PG + quad * 8];
                bf16x8 b21 = *(const bf16x8*)&sG[(32 + l15) * PG + 32 + quad * 8];
                pg0 = __builtin_amdgcn_mfma_f32_16x16x32_bf16(pa0, b00, pg0, 0, 0, 0);
                pg0 = __builtin_amdgcn_mfma_f32_16x16x32_bf16(pa1, b01, pg0, 0, 0, 0);
                pg1 = __builtin_amdgcn_mfma_f32_16x16x32_bf16(pa0, b10, pg1, 0, 0, 0);
                pg1 = __builtin_amdgcn_mfma_f32_16x16x32_bf16(pa1, b11, pg1, 0, 0, 0);
                pg2 = __builtin_amdgcn_mfma_f32_16x16x32_bf16(pa0, b20, pg2, 0, 0, 0);
                pg2 = __builtin_amdgcn_mfma_f32_16x16x32_bf16(pa1, b21, pg2, 0, 0, 0);
            }
            #pragma unroll
            for (int p = 0; p < 4; ++p) {
                int w = wave * 16 + quad * 4 + p;
                float s2 = pg0[p] * (float)sP[w * PP + l15]
                         + pg1[p] * (float)sP[w * PP + 16 + l15]
                         + pg2[p] * (float)sP[w * PP + 32 + l15];
                s2 = dpp_add16(s2);
                float w2v = sqrtf(fmaxf(s2, 0.f));
                float w1x = USE_WS ? w1v[p] : w1s[w];
                float rsim = w12v[p] / fmaxf(w1x * w2v, 1e-8f);
                if (l15 == 0) rs[w] = 6.0f * rsim;
            }
        } else {
            if (lane < NR) ssq[lane] = 0.f;   // reset for next iter (post-B2 reads, pre-next-B1)
        }
        __syncthreads();   // B4: rs complete

        // ---- wave 3: LSE epilogue (overlaps next staging of waves 0-2) ----
        if (wave == 3) {
            float v = (lane < NW) ? rs[lane] : -1e30f;
            float m = v;
            m = fmaxf(m, __shfl_xor(m, 1));  m = fmaxf(m, __shfl_xor(m, 2));
            m = fmaxf(m, __shfl_xor(m, 4));  m = fmaxf(m, __shfl_xor(m, 8));
            m = fmaxf(m, __shfl_xor(m, 16)); m = fmaxf(m, __shfl_xor(m, 32));
            float e = (lane < NW) ? __expf(v - m) : 0.f;
            e += __shfl_xor(e, 1);  e += __shfl_xor(e, 2);  e += __shfl_xor(e, 4);
            e += __shfl_xor(e, 8);  e += __shfl_xor(e, 16); e += __shfl_xor(e, 32);
            if (lane == 0) out[(size_t)i * NC + c] = (m + logf(e)) / 6.0f;
        }
    }
}

extern "C" void kernel_launch(void* const* d_in, const int* in_sizes, int n_in,
                              void* d_out, int out_size, void* d_ws, size_t ws_size,
                              hipStream_t stream) {
    const float* images   = (const float*)d_in[0];   // (128, 36, 256) fp32
    const float* captions = (const float*)d_in[1];   // (256, 48, 256) fp32
    float* out = (float*)d_out;                      // (128, 256) fp32

    const size_t need_w1  = (size_t)NC * NW * sizeof(float);   // 49152
    const size_t need_cap = (size_t)NC * NW * ND * 2;          // 6291456
    bool use_ws = ws_size >= need_w1 + need_cap;

    dim3 grid(1024), block(256);
    if (use_ws) {
        float* w1g = (float*)d_ws;
        bf16*  capb = (bf16*)((char*)d_ws + need_w1);
        hipLaunchKernelGGL(prep_kernel, dim3(NC), dim3(256), 0, stream, captions, capb, w1g);
        hipLaunchKernelGGL((scan_main<true>), grid, block, 0, stream, images, captions, capb, w1g, out);
    } else {
        hipLaunchKernelGGL((scan_main<false>), grid, block, 0, stream, images, captions,
                           (const bf16*)nullptr, (const float*)nullptr, out);
    }
}

// Round 6
// 325.791 us; speedup vs baseline: 2.6333x; 1.3321x over previous
//
#include <hip/hip_runtime.h>
#include <math.h>

#define NI 128
#define NC 256
#define NR 36
#define NW 48
#define ND 256

#define PCB 264      // sCb/sIb pitch (bf16): 528 B rows
#define PG  72       // sG pitch
#define PP  72       // sP pitch

typedef __bf16 bf16;
typedef __bf16 bf16x8 __attribute__((ext_vector_type(8)));
typedef __bf16 bf16x4 __attribute__((ext_vector_type(4)));
typedef float  f32x4  __attribute__((ext_vector_type(4)));

// LDS carve (bytes)
#define OFF_CB  0        // 48*264*2 = 25344 (sIb overlaid at init)
#define OFF_G   25344    // 6912 -> 32256
#define OFF_P   32256    // 6912 -> 39168
#define OFF_RS  39168    // 48*4 -> 39360
#define OFF_SSQ 39360    // 2*48*4 -> 39744
#define OFF_W1L 39744    // 32*48*4 = 6144 -> 45888
#define SMEM_TOTAL 45888 // 44.8 KB

#define MFMA16(A,B,C) __builtin_amdgcn_mfma_f32_16x16x32_bf16(A, B, C, 0, 0, 0)

__device__ __forceinline__ float dpp_add16(float v) {
    int x = __builtin_bit_cast(int, v);
    v += __builtin_bit_cast(float, __builtin_amdgcn_update_dpp(0, x, 0xB1, 0xF, 0xF, true));
    x = __builtin_bit_cast(int, v);
    v += __builtin_bit_cast(float, __builtin_amdgcn_update_dpp(0, x, 0x4E, 0xF, 0xF, true));
    x = __builtin_bit_cast(int, v);
    v += __builtin_bit_cast(float, __builtin_amdgcn_update_dpp(0, x, 0x141, 0xF, 0xF, true));
    x = __builtin_bit_cast(int, v);
    v += __builtin_bit_cast(float, __builtin_amdgcn_update_dpp(0, x, 0x140, 0xF, 0xF, true));
    return v;
}
__device__ __forceinline__ float dpp_max16(float v) {
    int x = __builtin_bit_cast(int, v);
    v = fmaxf(v, __builtin_bit_cast(float, __builtin_amdgcn_update_dpp(0, x, 0xB1, 0xF, 0xF, true)));
    x = __builtin_bit_cast(int, v);
    v = fmaxf(v, __builtin_bit_cast(float, __builtin_amdgcn_update_dpp(0, x, 0x4E, 0xF, 0xF, true)));
    x = __builtin_bit_cast(int, v);
    v = fmaxf(v, __builtin_bit_cast(float, __builtin_amdgcn_update_dpp(0, x, 0x141, 0xF, 0xF, true)));
    x = __builtin_bit_cast(int, v);
    v = fmaxf(v, __builtin_bit_cast(float, __builtin_amdgcn_update_dpp(0, x, 0x140, 0xF, 0xF, true)));
    return v;
}

// ---- prep: captions fp32 -> bf16 cache + per-caption-row L2 norms (1024 blocks) ----
__global__ __launch_bounds__(256)
void prep_kernel(const float* __restrict__ captions, bf16* __restrict__ capb,
                 float* __restrict__ w1g)
{
    const int c = blockIdx.x >> 2, q = blockIdx.x & 3;
    const int wave = threadIdx.x >> 6, lane = threadIdx.x & 63;
    #pragma unroll
    for (int j = 0; j < 3; ++j) {
        int w = q * 12 + wave * 3 + j;
        size_t off = ((size_t)c * NW + w) * ND + lane * 4;
        float4 v = *(const float4*)(captions + off);
        bf16x4 h = { (bf16)v.x, (bf16)v.y, (bf16)v.z, (bf16)v.w };
        *(bf16x4*)(capb + off) = h;
        float s = v.x*v.x + v.y*v.y + v.z*v.z + v.w*v.w;
        s += __shfl_xor(s, 1);  s += __shfl_xor(s, 2);  s += __shfl_xor(s, 4);
        s += __shfl_xor(s, 8);  s += __shfl_xor(s, 16); s += __shfl_xor(s, 32);
        if (lane == 0) w1g[c * NW + w] = sqrtf(s);
    }
}

template<bool USE_WS>
__global__ __launch_bounds__(256, 2)   // 2 waves/EU: up to 256 VGPR -> ibf stays in registers (R5 spilled at cap 170)
void scan_main(const float* __restrict__ images,
               const float* __restrict__ captions,
               const bf16* __restrict__ capb,
               const float* __restrict__ w1g,
               float* __restrict__ out)
{
    __shared__ __align__(16) unsigned char smem[SMEM_TOTAL];
    bf16*  sCb = (bf16*)(smem + OFF_CB);    // [w][d] caption rows; wave w owns rows [16w,16w+16)
    bf16*  sIb = (bf16*)(smem + OFF_CB);    // init overlay: image rows
    bf16*  sG  = (bf16*)(smem + OFF_G);     // Gram, pads zeroed
    bf16*  sP  = (bf16*)(smem + OFF_P);     // probs; wave-private rows
    float* rs  = (float*)(smem + OFF_RS);
    float* ssq = (float*)(smem + OFF_SSQ);  // [2][48] parity double-buffer
    float* sW1 = (float*)(smem + OFF_W1L);  // USE_WS: [32][48]; else [48]

    const int tid  = threadIdx.x;
    const int wave = tid >> 6;
    const int lane = tid & 63;
    const int quad = lane >> 4;
    const int l15  = lane & 15;
    const int i    = blockIdx.x >> 3;
    const int c0   = (blockIdx.x & 7) * 32;   // chunk == XCD id -> L2-pinned captions

    // ---- init: stage image, zero pads/buffers, load w1 cache ----
    const float* gI = images + (size_t)i * NR * ND;
    #pragma unroll
    for (int k = 0; k < 9; ++k) {
        int t = tid + k * 256;
        int e = t * 4, r = e >> 8, d = e & 255;
        float4 v = *(const float4*)(gI + e);
        bf16x4 h = { (bf16)v.x, (bf16)v.y, (bf16)v.z, (bf16)v.w };
        *(bf16x4*)&sIb[r * PCB + d] = h;
    }
    {
        uint32_t* pIb = (uint32_t*)sIb;       // image rows 36..47 -> 0
        #pragma unroll
        for (int k = 0; k < 7; ++k) { int x = tid + k * 256; if (x < 1584) pIb[4752 + x] = 0u; }
        uint32_t* pG = (uint32_t*)sG;         // whole Gram (col-pad stays 0)
        #pragma unroll
        for (int k = 0; k < 14; ++k) { int x = tid + k * 256; if (x < 3456) pG[x] = 0u; }
        if (tid < 192) {                      // sP k-pad 48..63
            int w = tid >> 2, j = tid & 3;
            bf16x4 z = { (bf16)0.f, (bf16)0.f, (bf16)0.f, (bf16)0.f };
            *(bf16x4*)&sP[w * PP + 48 + j * 4] = z;
        }
        if (tid < 96) ssq[tid] = 0.f;
        if (USE_WS) {
            #pragma unroll
            for (int k = 0; k < 2; ++k) {
                int t = tid + k * 256;
                if (t < 384) {
                    float4 v = *(const float4*)(w1g + (size_t)c0 * NW + t * 4);
                    *(float4*)&sW1[t * 4] = v;
                }
            }
        }
    }
    __syncthreads();   // B0

    // ---- once: Gram G = I*I^T (pads -> clean zeros) + image B-frags into registers ----
    bf16x8 ibf[3][8];
    uint4 cr[8];
    if (wave < 3) {
        f32x4 g0 = {0,0,0,0}, g1 = {0,0,0,0}, g2 = {0,0,0,0};
        #pragma unroll
        for (int ks = 0; ks < 8; ++ks) {
            bf16x8 a  = *(const bf16x8*)&sIb[(wave * 16 + l15) * PCB + ks * 32 + quad * 8];
            bf16x8 b0 = *(const bf16x8*)&sIb[(l15)      * PCB + ks * 32 + quad * 8];
            bf16x8 b1 = *(const bf16x8*)&sIb[(16 + l15) * PCB + ks * 32 + quad * 8];
            bf16x8 b2 = *(const bf16x8*)&sIb[(32 + l15) * PCB + ks * 32 + quad * 8];
            g0 = MFMA16(a, b0, g0); g1 = MFMA16(a, b1, g1); g2 = MFMA16(a, b2, g2);
        }
        #pragma unroll
        for (int p = 0; p < 4; ++p) {
            int m = wave * 16 + quad * 4 + p;
            sG[m * PG + l15]      = (bf16)g0[p];
            sG[m * PG + 16 + l15] = (bf16)g1[p];
            sG[m * PG + 32 + l15] = (bf16)g2[p];
        }
        #pragma unroll
        for (int nt = 0; nt < 3; ++nt)
            #pragma unroll
            for (int ks = 0; ks < 8; ++ks)
                ibf[nt][ks] = *(const bf16x8*)&sIb[(nt * 16 + l15) * PCB + ks * 32 + quad * 8];
        if (USE_WS) {   // prefetch caption c0 while Gram finishes
            const bf16* src = capb + (size_t)c0 * (NW * ND);
            #pragma unroll
            for (int j = 0; j < 8; ++j)
                cr[j] = *(const uint4*)(src + (wave * 16 + j * 2 + (lane >> 5)) * ND + (lane & 31) * 8);
        }
    }
    __syncthreads();   // B1: sG published; sIb reads done -> region becomes sCb

    if (wave < 3) {
        if (USE_WS) {
            #pragma unroll
            for (int j = 0; j < 8; ++j)
                *(uint4*)&sCb[(wave * 16 + j * 2 + (lane >> 5)) * PCB + (lane & 31) * 8] = cr[j];
        } else {
            const float* src = captions + (size_t)c0 * NW * ND;
            #pragma unroll
            for (int j = 0; j < 16; ++j) {
                int w = wave * 16 + j;
                float4 v = *(const float4*)(src + w * ND + lane * 4);
                bf16x4 h = { (bf16)v.x, (bf16)v.y, (bf16)v.z, (bf16)v.w };
                *(bf16x4*)&sCb[w * PCB + lane * 4] = h;
                float s = v.x*v.x + v.y*v.y + v.z*v.z + v.w*v.w;
                s += __shfl_xor(s, 1);  s += __shfl_xor(s, 2);  s += __shfl_xor(s, 4);
                s += __shfl_xor(s, 8);  s += __shfl_xor(s, 16); s += __shfl_xor(s, 32);
                if (lane == 0) sW1[w] = sqrtf(s);
            }
        }
    }

    for (int it = 0; it < 32; ++it) {
        const int c = c0 + it;
        const int par = it & 1;
        float* ssqp = ssq + par * 48;

        float xr[3][4], q0[4], q1[4], q2[4], w12v[4];

        if (wave < 3) {
            if (!USE_WS && it > 0) {       // fallback: stage current caption fp32->bf16
                const float* src = captions + (size_t)c * NW * ND;
                #pragma unroll
                for (int j = 0; j < 16; ++j) {
                    int w = wave * 16 + j;
                    float4 v = *(const float4*)(src + w * ND + lane * 4);
                    bf16x4 h = { (bf16)v.x, (bf16)v.y, (bf16)v.z, (bf16)v.w };
                    *(bf16x4*)&sCb[w * PCB + lane * 4] = h;
                    float s = v.x*v.x + v.y*v.y + v.z*v.z + v.w*v.w;
                    s += __shfl_xor(s, 1);  s += __shfl_xor(s, 2);  s += __shfl_xor(s, 4);
                    s += __shfl_xor(s, 8);  s += __shfl_xor(s, 16); s += __shfl_xor(s, 32);
                    if (lane == 0) sW1[w] = sqrtf(s);
                }
            }
            // ---- A-frags for current caption (own rows -> same-wave RAW, no barrier) ----
            bf16x8 af[8];
            #pragma unroll
            for (int ks = 0; ks < 8; ++ks)
                af[ks] = *(const bf16x8*)&sCb[(wave * 16 + l15) * PCB + ks * 32 + quad * 8];
            // ---- prefetch next caption into registers (hidden behind softmax/phase2) ----
            if (USE_WS) {
                int cn = (c + 1 < NC) ? c + 1 : NC - 1;
                const bf16* src = capb + (size_t)cn * (NW * ND);
                #pragma unroll
                for (int j = 0; j < 8; ++j)
                    cr[j] = *(const uint4*)(src + (wave * 16 + j * 2 + (lane >> 5)) * ND + (lane & 31) * 8);
            }
            // ---- phase 1: attnT = leaky(C * I^T) ----
            f32x4 a0 = {0,0,0,0}, a1 = {0,0,0,0}, a2 = {0,0,0,0};
            #pragma unroll
            for (int ks = 0; ks < 8; ++ks) {
                a0 = MFMA16(af[ks], ibf[0][ks], a0);
                a1 = MFMA16(af[ks], ibf[1][ks], a1);
                a2 = MFMA16(af[ks], ibf[2][ks], a2);
            }
            float p0 = 0.f, p1 = 0.f, p2 = 0.f;
            #pragma unroll
            for (int p = 0; p < 4; ++p) {
                float t0 = a0[p]; t0 = t0 > 0.f ? t0 : 0.1f * t0; xr[0][p] = t0; p0 += t0 * t0;
                float t1 = a1[p]; t1 = t1 > 0.f ? t1 : 0.1f * t1; xr[1][p] = t1; p1 += t1 * t1;
                float t2 = a2[p]; t2 = t2 > 0.f ? t2 : 0.1f * t2; xr[2][p] = t2; p2 += t2 * t2;
            }
            p0 += __shfl_xor(p0, 16); p0 += __shfl_xor(p0, 32);
            p1 += __shfl_xor(p1, 16); p1 += __shfl_xor(p1, 32);
            p2 += __shfl_xor(p2, 16); p2 += __shfl_xor(p2, 32);
            if (quad == 0) {
                atomicAdd(&ssqp[l15], p0);
                atomicAdd(&ssqp[16 + l15], p1);
                if (l15 < 4) atomicAdd(&ssqp[32 + l15], p2);
            }
        }
        __syncthreads();   // B2: ssq complete

        if (wave == 3) {
            if (lane < 48) ssq[(par ^ 1) * 48 + lane] = 0.f;   // clean buffer for it+1
        } else {
            // ---- softmax (registers + DPP); w12 from raw logits ----
            float inv0 = 1.f / (sqrtf(ssqp[l15]) + 1e-8f);
            float inv1 = 1.f / (sqrtf(ssqp[16 + l15]) + 1e-8f);
            float inv2 = (l15 < 4) ? 1.f / (sqrtf(ssqp[32 + l15]) + 1e-8f) : 0.f;
            #pragma unroll
            for (int p = 0; p < 4; ++p) {
                float raw0 = xr[0][p] > 0.f ? xr[0][p] : 10.f * xr[0][p];
                float raw1 = xr[1][p] > 0.f ? xr[1][p] : 10.f * xr[1][p];
                float raw2 = xr[2][p] > 0.f ? xr[2][p] : 10.f * xr[2][p];
                float x0 = xr[0][p] * inv0 * 9.0f;
                float x1 = xr[1][p] * inv1 * 9.0f;
                float x2 = (l15 < 4) ? xr[2][p] * inv2 * 9.0f : -1e30f;
                float m = dpp_max16(fmaxf(fmaxf(x0, x1), x2));
                float e0 = __expf(x0 - m), e1 = __expf(x1 - m);
                float e2 = (l15 < 4) ? __expf(x2 - m) : 0.f;
                float s   = dpp_add16(e0 + e1 + e2);
                float num = dpp_add16(e0 * raw0 + e1 * raw1 + e2 * raw2);
                float is = 1.f / s;
                w12v[p] = num * is;
                q0[p] = e0 * is; q1[p] = e1 * is; q2[p] = e2 * is;
                int w = wave * 16 + quad * 4 + p;
                sP[w * PP + l15]      = (bf16)q0[p];
                sP[w * PP + 16 + l15] = (bf16)q1[p];
                sP[w * PP + 32 + l15] = (bf16)q2[p];
            }
            // ---- phase 2: PG MFMA (own sP rows, same-wave RAW); w2 via register dot + DPP ----
            const bf16* ap2 = &sP[(wave * 16 + l15) * PP];
            bf16x8 pa0 = *(const bf16x8*)(ap2 + quad * 8);
            bf16x8 pa1 = *(const bf16x8*)(ap2 + 32 + quad * 8);
            f32x4 pg0 = {0,0,0,0}, pg1 = {0,0,0,0}, pg2 = {0,0,0,0};
            {
                bf16x8 b00 = *(const bf16x8*)&sG[(l15) * PG + quad * 8];
                bf16x8 b01 = *(const bf16x8*)&sG[(l15) * PG + 32 + quad * 8];
                bf16x8 b10 = *(const bf16x8*)&sG[(16 + l15) * PG + quad * 8];
                bf16x8 b11 = *(const bf16x8*)&sG[(16 + l15) * PG + 32 + quad * 8];
                bf16x8 b20 = *(const bf16x8*)&sG[(32 + l15) * PG + quad * 8];
                bf16x8 b21 = *(const bf16x8*)&sG[(32 + l15) * PG + 32 + quad * 8];
                pg0 = MFMA16(pa0, b00, pg0); pg0 = MFMA16(pa1, b01, pg0);
                pg1 = MFMA16(pa0, b10, pg1); pg1 = MFMA16(pa1, b11, pg1);
                pg2 = MFMA16(pa0, b20, pg2); pg2 = MFMA16(pa1, b21, pg2);
            }
            const int w1base = USE_WS ? it * NW : 0;
            #pragma unroll
            for (int p = 0; p < 4; ++p) {
                float s2 = pg0[p] * q0[p] + pg1[p] * q1[p] + pg2[p] * q2[p];
                s2 = dpp_add16(s2);
                int w = wave * 16 + quad * 4 + p;
                float w2v = sqrtf(fmaxf(s2, 0.f));
                float w1x = sW1[w1base + w];
                float rsim = w12v[p] / fmaxf(w1x * w2v, 1e-8f);
                if (l15 == 0) rs[w] = 6.0f * rsim;
            }
            // ---- stage prefetched caption it+1 into own rows (consumed after B4) ----
            if (USE_WS) {
                #pragma unroll
                for (int j = 0; j < 8; ++j)
                    *(uint4*)&sCb[(wave * 16 + j * 2 + (lane >> 5)) * PCB + (lane & 31) * 8] = cr[j];
            }
        }
        __syncthreads();   // B4: rs complete

        // ---- wave 3: LSE epilogue (overlaps waves 0-2's next iteration) ----
        if (wave == 3) {
            float v = (lane < NW) ? rs[lane] : -1e30f;
            float m = v;
            m = fmaxf(m, __shfl_xor(m, 1));  m = fmaxf(m, __shfl_xor(m, 2));
            m = fmaxf(m, __shfl_xor(m, 4));  m = fmaxf(m, __shfl_xor(m, 8));
            m = fmaxf(m, __shfl_xor(m, 16)); m = fmaxf(m, __shfl_xor(m, 32));
            float e = (lane < NW) ? __expf(v - m) : 0.f;
            e += __shfl_xor(e, 1);  e += __shfl_xor(e, 2);  e += __shfl_xor(e, 4);
            e += __shfl_xor(e, 8);  e += __shfl_xor(e, 16); e += __shfl_xor(e, 32);
            if (lane == 0) out[(size_t)i * NC + c] = (m + logf(e)) / 6.0f;
        }
    }
}

extern "C" void kernel_launch(void* const* d_in, const int* in_sizes, int n_in,
                              void* d_out, int out_size, void* d_ws, size_t ws_size,
                              hipStream_t stream) {
    const float* images   = (const float*)d_in[0];   // (128, 36, 256) fp32
    const float* captions = (const float*)d_in[1];   // (256, 48, 256) fp32
    float* out = (float*)d_out;                      // (128, 256) fp32

    const size_t need_w1  = (size_t)NC * NW * sizeof(float);   // 49152
    const size_t need_cap = (size_t)NC * NW * ND * 2;          // 6291456
    bool use_ws = ws_size >= need_w1 + need_cap;

    dim3 grid(1024), block(256);
    if (use_ws) {
        float* w1g = (float*)d_ws;
        bf16*  capb = (bf16*)((char*)d_ws + need_w1);
        hipLaunchKernelGGL(prep_kernel, dim3(1024), dim3(256), 0, stream, captions, capb, w1g);
        hipLaunchKernelGGL((scan_main<true>), grid, block, 0, stream, images, captions, capb, w1g, out);
    } else {
        hipLaunchKernelGGL((scan_main<false>), grid, block, 0, stream, images, captions,
                           (const bf16*)nullptr, (const float*)nullptr, out);
    }
}

// Round 7
// 204.033 us; speedup vs baseline: 4.2047x; 1.5968x over previous
//
#include <hip/hip_runtime.h>
#include <math.h>

#define NI 128
#define NC 256
#define NR 36
#define NW 48
#define ND 256

#define PIB 264      // sIb pitch (bf16): 528 B rows, 16B-aligned, ~2-way banks
#define PG  72       // sG pitch: cols 48..71 stay zero (k-pad for phase-2)
#define PSP 40       // sP pitch (k-compact): cols 36..39 zeroed; k=40..63 reads land on
                     // finite neighbor data x sG zeros (provably 0 contribution)

typedef __bf16 bf16;
typedef __bf16 bf16x8 __attribute__((ext_vector_type(8)));
typedef __bf16 bf16x4 __attribute__((ext_vector_type(4)));
typedef float  f32x4  __attribute__((ext_vector_type(4)));

// LDS carve (bytes)
#define OFF_IB    0        // 48*264*2 = 25344
#define OFF_G     25344    // 48*72*2  = 6912  -> 32256
#define OFF_P     32256    // 4 wave-private bufs: 4*48*40*2 = 15360 -> 47616
#define OFF_GUARD 47616    // 128 B zero tail (sP row-47 overread guard)
#define SMEM_TOTAL 47744   // 46.6 KB -> 3 blocks/CU

#define MFMA16(A,B,C) __builtin_amdgcn_mfma_f32_16x16x32_bf16(A, B, C, 0, 0, 0)

__device__ __forceinline__ float dpp_add16(float v) {
    int x = __builtin_bit_cast(int, v);
    v += __builtin_bit_cast(float, __builtin_amdgcn_update_dpp(0, x, 0xB1, 0xF, 0xF, true));
    x = __builtin_bit_cast(int, v);
    v += __builtin_bit_cast(float, __builtin_amdgcn_update_dpp(0, x, 0x4E, 0xF, 0xF, true));
    x = __builtin_bit_cast(int, v);
    v += __builtin_bit_cast(float, __builtin_amdgcn_update_dpp(0, x, 0x141, 0xF, 0xF, true));
    x = __builtin_bit_cast(int, v);
    v += __builtin_bit_cast(float, __builtin_amdgcn_update_dpp(0, x, 0x140, 0xF, 0xF, true));
    return v;
}
__device__ __forceinline__ float dpp_max16(float v) {
    int x = __builtin_bit_cast(int, v);
    v = fmaxf(v, __builtin_bit_cast(float, __builtin_amdgcn_update_dpp(0, x, 0xB1, 0xF, 0xF, true)));
    x = __builtin_bit_cast(int, v);
    v = fmaxf(v, __builtin_bit_cast(float, __builtin_amdgcn_update_dpp(0, x, 0x4E, 0xF, 0xF, true)));
    x = __builtin_bit_cast(int, v);
    v = fmaxf(v, __builtin_bit_cast(float, __builtin_amdgcn_update_dpp(0, x, 0x141, 0xF, 0xF, true)));
    x = __builtin_bit_cast(int, v);
    v = fmaxf(v, __builtin_bit_cast(float, __builtin_amdgcn_update_dpp(0, x, 0x140, 0xF, 0xF, true)));
    return v;
}

// ---- prep: captions fp32 -> bf16 cache + per-caption-row L2 norms ----
__global__ __launch_bounds__(256)
void prep_kernel(const float* __restrict__ captions, bf16* __restrict__ capb,
                 float* __restrict__ w1g)
{
    const int c = blockIdx.x >> 2, q = blockIdx.x & 3;
    const int wave = threadIdx.x >> 6, lane = threadIdx.x & 63;
    #pragma unroll
    for (int j = 0; j < 3; ++j) {
        int w = q * 12 + wave * 3 + j;
        size_t off = ((size_t)c * NW + w) * ND + lane * 4;
        float4 v = *(const float4*)(captions + off);
        bf16x4 h = { (bf16)v.x, (bf16)v.y, (bf16)v.z, (bf16)v.w };
        *(bf16x4*)(capb + off) = h;
        float s = v.x*v.x + v.y*v.y + v.z*v.z + v.w*v.w;
        s += __shfl_xor(s, 1);  s += __shfl_xor(s, 2);  s += __shfl_xor(s, 4);
        s += __shfl_xor(s, 8);  s += __shfl_xor(s, 16); s += __shfl_xor(s, 32);
        if (lane == 0) w1g[c * NW + w] = sqrtf(s);
    }
}

__device__ __forceinline__ bf16x8 ld_cvt_f32(const float* p, float& ss) {
    float4 lo = *(const float4*)p;
    float4 hi = *(const float4*)(p + 4);
    ss += lo.x*lo.x + lo.y*lo.y + lo.z*lo.z + lo.w*lo.w
        + hi.x*hi.x + hi.y*hi.y + hi.z*hi.z + hi.w*hi.w;
    bf16x8 r = { (bf16)lo.x, (bf16)lo.y, (bf16)lo.z, (bf16)lo.w,
                 (bf16)hi.x, (bf16)hi.y, (bf16)hi.z, (bf16)hi.w };
    return r;
}

template<bool USE_WS>
__global__ __launch_bounds__(256, 3)   // 3 blocks/CU (LDS 46.6KB x3), VGPR cap ~170 — demand ~140, no spill
void scan_main(const float* __restrict__ images,
               const float* __restrict__ captions,
               const bf16* __restrict__ capb,
               const float* __restrict__ w1g,
               float* __restrict__ out)
{
    __shared__ __align__(16) unsigned char smem[SMEM_TOTAL];
    bf16* sIb = (bf16*)(smem + OFF_IB);   // [r][d] image, rows 36..47 zeroed (persistent)
    bf16* sG  = (bf16*)(smem + OFF_G);    // [r'][r] Gram, cols/rows >=36 clean zeros
    // sP: wave-private [48][PSP], below

    const int tid  = threadIdx.x;
    const int wave = tid >> 6;
    const int lane = tid & 63;
    const int quad = lane >> 4;
    const int l15  = lane & 15;
    const int i    = blockIdx.x >> 3;
    const int c0   = (blockIdx.x & 7) * 32;   // chunk == blockIdx%8 -> XCD-pinned captions

    bf16* sPw = (bf16*)(smem + OFF_P) + wave * (48 * PSP);

    // ---- init: stage image bf16, zero pads / sG / sP+guard ----
    const float* gI = images + (size_t)i * NR * ND;
    #pragma unroll
    for (int k = 0; k < 9; ++k) {
        int t = tid + k * 256;               // 2304 float4
        int e = t * 4, r = e >> 8, d = e & 255;
        float4 v = *(const float4*)(gI + e);
        bf16x4 h = { (bf16)v.x, (bf16)v.y, (bf16)v.z, (bf16)v.w };
        *(bf16x4*)&sIb[r * PIB + d] = h;
    }
    {
        uint32_t* pIb = (uint32_t*)sIb;      // rows 36..47 -> 0 (dwords 4752..6335)
        #pragma unroll
        for (int k = 0; k < 7; ++k) { int x = tid + k * 256; if (x < 1584) pIb[4752 + x] = 0u; }
        uint32_t* pG = (uint32_t*)sG;        // whole sG (1728 dwords)
        #pragma unroll
        for (int k = 0; k < 7; ++k) { int x = tid + k * 256; if (x < 1728) pG[x] = 0u; }
        uint32_t* pP = (uint32_t*)(smem + OFF_P);   // whole sP region + guard (3872 dwords)
        #pragma unroll
        for (int k = 0; k < 16; ++k) { int x = tid + k * 256; if (x < 3872) pP[x] = 0u; }
    }
    __syncthreads();   // B0

    // ---- once: Gram G = I*I^T (waves 0-2); pads become clean zeros ----
    if (wave < 3) {
        f32x4 g0 = {0,0,0,0}, g1 = {0,0,0,0}, g2 = {0,0,0,0};
        #pragma unroll
        for (int ks = 0; ks < 8; ++ks) {
            bf16x8 a  = *(const bf16x8*)&sIb[(wave * 16 + l15) * PIB + ks * 32 + quad * 8];
            bf16x8 b0 = *(const bf16x8*)&sIb[(l15)      * PIB + ks * 32 + quad * 8];
            bf16x8 b1 = *(const bf16x8*)&sIb[(16 + l15) * PIB + ks * 32 + quad * 8];
            bf16x8 b2 = *(const bf16x8*)&sIb[(32 + l15) * PIB + ks * 32 + quad * 8];
            g0 = MFMA16(a, b0, g0); g1 = MFMA16(a, b1, g1); g2 = MFMA16(a, b2, g2);
        }
        #pragma unroll
        for (int p = 0; p < 4; ++p) {
            int m = wave * 16 + quad * 4 + p;
            sG[m * PG + l15]      = (bf16)g0[p];
            sG[m * PG + 16 + l15] = (bf16)g1[p];
            sG[m * PG + 32 + l15] = (bf16)g2[p];
        }
    }
    __syncthreads();   // B1: sG published. No further barriers — waves fully independent.

    // ---- per-wave: 8 captions, everything in-wave ----
    for (int it = 0; it < 8; ++it) {
        const int c = c0 + wave * 8 + it;

        // w1 (caption row norms): precomputed (USE_WS) or computed from fp32 loads
        float w1v[3][4];
        if (USE_WS) {
            #pragma unroll
            for (int mt = 0; mt < 3; ++mt)
                #pragma unroll
                for (int p = 0; p < 4; ++p)
                    w1v[mt][p] = w1g[(size_t)c * NW + mt * 16 + quad * 4 + p];
        }

        // ---- phase 1: attnT[w][r] = C_c · I^T, A from global, B from LDS ----
        f32x4 acc[3][3] = {};
        float ssc[3] = {0.f, 0.f, 0.f};      // !USE_WS: per-lane partial cap-norm
        const bf16*  ab  = USE_WS ? capb + ((size_t)c * NW + l15) * ND + quad * 8 : nullptr;
        const float* ab32 = USE_WS ? nullptr : captions + ((size_t)c * NW + l15) * ND + quad * 8;
        #pragma unroll
        for (int ks = 0; ks < 8; ++ks) {
            bf16x8 a0, a1, a2;
            if (USE_WS) {
                a0 = *(const bf16x8*)(ab + ks * 32);
                a1 = *(const bf16x8*)(ab + 16 * ND + ks * 32);
                a2 = *(const bf16x8*)(ab + 32 * ND + ks * 32);
            } else {
                a0 = ld_cvt_f32(ab32 + ks * 32, ssc[0]);
                a1 = ld_cvt_f32(ab32 + 16 * ND + ks * 32, ssc[1]);
                a2 = ld_cvt_f32(ab32 + 32 * ND + ks * 32, ssc[2]);
            }
            bf16x8 b0 = *(const bf16x8*)&sIb[(l15)      * PIB + ks * 32 + quad * 8];
            bf16x8 b1 = *(const bf16x8*)&sIb[(16 + l15) * PIB + ks * 32 + quad * 8];
            bf16x8 b2 = *(const bf16x8*)&sIb[(32 + l15) * PIB + ks * 32 + quad * 8];
            acc[0][0] = MFMA16(a0, b0, acc[0][0]);
            acc[1][0] = MFMA16(a1, b0, acc[1][0]);
            acc[2][0] = MFMA16(a2, b0, acc[2][0]);
            acc[0][1] = MFMA16(a0, b1, acc[0][1]);
            acc[1][1] = MFMA16(a1, b1, acc[1][1]);
            acc[2][1] = MFMA16(a2, b1, acc[2][1]);
            acc[0][2] = MFMA16(a0, b2, acc[0][2]);
            acc[1][2] = MFMA16(a1, b2, acc[1][2]);
            acc[2][2] = MFMA16(a2, b2, acc[2][2]);
        }
        if (!USE_WS) {
            #pragma unroll
            for (int mt = 0; mt < 3; ++mt) {
                float s = ssc[mt];
                s += __shfl_xor(s, 16); s += __shfl_xor(s, 32);   // quad reduce -> full row norm^2
                ssc[mt] = sqrtf(s);                               // w1 for row mt*16+l15
            }
            #pragma unroll
            for (int mt = 0; mt < 3; ++mt)
                #pragma unroll
                for (int p = 0; p < 4; ++p)
                    w1v[mt][p] = __shfl(ssc[mt], (lane & 48) + quad * 4 + p);
        }

        // ---- leaky + l2norm (over w) : all in-wave ----
        float xr[3][3][4];                   // [mt][nt][p]: w=mt*16+quad*4+p, r=nt*16+l15
        #pragma unroll
        for (int mt = 0; mt < 3; ++mt)
            #pragma unroll
            for (int nt = 0; nt < 3; ++nt)
                #pragma unroll
                for (int p = 0; p < 4; ++p) {
                    float t = acc[mt][nt][p];
                    xr[mt][nt][p] = t > 0.f ? t : 0.1f * t;
                }
        float inv[3];
        #pragma unroll
        for (int nt = 0; nt < 3; ++nt) {
            float s = 0.f;
            #pragma unroll
            for (int mt = 0; mt < 3; ++mt)
                #pragma unroll
                for (int p = 0; p < 4; ++p) { float t = xr[mt][nt][p]; s += t * t; }
            s += __shfl_xor(s, 16); s += __shfl_xor(s, 32);       // sum over w-quads
            inv[nt] = 1.f / (sqrtf(s) + 1e-8f);
        }

        // ---- softmax over r per w (DPP16 over l15, local over nt); w12 from raw ----
        float q[3][3][4];                    // probs, C-layout
        float w12v[3][4];
        #pragma unroll
        for (int mt = 0; mt < 3; ++mt) {
            #pragma unroll
            for (int p = 0; p < 4; ++p) {
                float v0 = xr[mt][0][p], v1 = xr[mt][1][p], v2 = xr[mt][2][p];
                float raw0 = v0 > 0.f ? v0 : 10.f * v0;
                float raw1 = v1 > 0.f ? v1 : 10.f * v1;
                float raw2 = v2 > 0.f ? v2 : 10.f * v2;
                float x0 = v0 * inv[0] * 9.0f;
                float x1 = v1 * inv[1] * 9.0f;
                float x2 = (l15 < 4) ? v2 * inv[2] * 9.0f : -1e30f;   // mask r>=36
                float m = dpp_max16(fmaxf(fmaxf(x0, x1), x2));
                float e0 = __expf(x0 - m), e1 = __expf(x1 - m);
                float e2 = (l15 < 4) ? __expf(x2 - m) : 0.f;
                float s   = dpp_add16(e0 + e1 + e2);
                float num = dpp_add16(e0 * raw0 + e1 * raw1 + e2 * raw2);
                float is = 1.f / s;
                w12v[mt][p] = num * is;
                q[mt][0][p] = e0 * is; q[mt][1][p] = e1 * is; q[mt][2][p] = e2 * is;
                int row = mt * 16 + quad * 4 + p;
                sPw[row * PSP + l15]      = (bf16)q[mt][0][p];
                sPw[row * PSP + 16 + l15] = (bf16)q[mt][1][p];
                if (l15 < 4) sPw[row * PSP + 32 + l15] = (bf16)q[mt][2][p];   // cols 36..39 stay 0
            }
        }
        // same-wave RAW on sPw -> compiler inserts lgkmcnt; no barrier

        // ---- phase 2: PG = P·G (K=64; k>=36 contributions provably 0) ----
        bf16x8 bg0[3], bg1[3];
        #pragma unroll
        for (int nt = 0; nt < 3; ++nt) {
            bg0[nt] = *(const bf16x8*)&sG[(nt * 16 + l15) * PG + quad * 8];
            bg1[nt] = *(const bf16x8*)&sG[(nt * 16 + l15) * PG + 32 + quad * 8];
        }
        f32x4 pg[3][3] = {};
        #pragma unroll
        for (int mt = 0; mt < 3; ++mt) {
            const bf16* ap = &sPw[(mt * 16 + l15) * PSP];
            bf16x8 pa0 = *(const bf16x8*)(ap + quad * 8);
            bf16x8 pa1 = *(const bf16x8*)(ap + 32 + quad * 8);   // overreads: finite x sG-zeros
            #pragma unroll
            for (int nt = 0; nt < 3; ++nt) {
                pg[mt][nt] = MFMA16(pa0, bg0[nt], pg[mt][nt]);
                pg[mt][nt] = MFMA16(pa1, bg1[nt], pg[mt][nt]);
            }
        }

        // ---- w2, rsim, LSE: all in-wave ----
        float lv[3][4];
        #pragma unroll
        for (int mt = 0; mt < 3; ++mt) {
            #pragma unroll
            for (int p = 0; p < 4; ++p) {
                float s2 = pg[mt][0][p] * q[mt][0][p]
                         + pg[mt][1][p] * q[mt][1][p]
                         + pg[mt][2][p] * q[mt][2][p];
                s2 = dpp_add16(s2);
                float w2v = sqrtf(fmaxf(s2, 0.f));
                float rsim = w12v[mt][p] / fmaxf(w1v[mt][p] * w2v, 1e-8f);
                lv[mt][p] = 6.0f * rsim;
            }
        }
        float m = -1e30f;
        #pragma unroll
        for (int mt = 0; mt < 3; ++mt)
            #pragma unroll
            for (int p = 0; p < 4; ++p) m = fmaxf(m, lv[mt][p]);
        m = fmaxf(m, __shfl_xor(m, 16)); m = fmaxf(m, __shfl_xor(m, 32));   // over quads
        float e = 0.f;
        #pragma unroll
        for (int mt = 0; mt < 3; ++mt)
            #pragma unroll
            for (int p = 0; p < 4; ++p) e += __expf(lv[mt][p] - m);
        e += __shfl_xor(e, 16); e += __shfl_xor(e, 32);
        if (lane == 0) out[(size_t)i * NC + c] = (m + logf(e)) / 6.0f;
    }
}

extern "C" void kernel_launch(void* const* d_in, const int* in_sizes, int n_in,
                              void* d_out, int out_size, void* d_ws, size_t ws_size,
                              hipStream_t stream) {
    const float* images   = (const float*)d_in[0];   // (128, 36, 256) fp32
    const float* captions = (const float*)d_in[1];   // (256, 48, 256) fp32
    float* out = (float*)d_out;                      // (128, 256) fp32

    const size_t need_w1  = (size_t)NC * NW * sizeof(float);   // 49152
    const size_t need_cap = (size_t)NC * NW * ND * 2;          // 6291456
    bool use_ws = ws_size >= need_w1 + need_cap;

    dim3 grid(1024), block(256);
    if (use_ws) {
        float* w1g = (float*)d_ws;
        bf16*  capb = (bf16*)((char*)d_ws + need_w1);
        hipLaunchKernelGGL(prep_kernel, dim3(1024), dim3(256), 0, stream, captions, capb, w1g);
        hipLaunchKernelGGL((scan_main<true>), grid, block, 0, stream, images, captions, capb, w1g, out);
    } else {
        hipLaunchKernelGGL((scan_main<false>), grid, block, 0, stream, images, captions,
                           (const bf16*)nullptr, (const float*)nullptr, out);
    }
}

// Round 8
// 187.324 us; speedup vs baseline: 4.5798x; 1.0892x over previous
//
#include <hip/hip_runtime.h>
#include <math.h>

#define NI 128
#define NC 256
#define NR 36
#define NW 48
#define ND 256

#define PIB 264      // sIb pitch (bf16): 528 B rows, 16B-aligned, ~2-way banks
#define PG  72       // sG pitch: cols 48..71 stay zero (k-pad for phase-2)
#define PSP 40       // sP pitch (k-compact): cols 36..39 zeroed; k=40..63 reads land on
                     // finite neighbor data x sG zeros (provably 0 contribution)

// 9 (lambda_softmax) * log2(e): exp(9*x) == exp2(SOFT_SCALE*x)
#define SOFT_SCALE 12.984255368000671f

typedef __bf16 bf16;
typedef __bf16 bf16x8 __attribute__((ext_vector_type(8)));
typedef __bf16 bf16x4 __attribute__((ext_vector_type(4)));
typedef float  f32x4  __attribute__((ext_vector_type(4)));

// LDS carve (bytes)
#define OFF_IB    0        // 48*264*2 = 25344
#define OFF_G     25344    // 48*72*2  = 6912  -> 32256
#define OFF_P     32256    // 4 wave-private bufs: 4*48*40*2 = 15360 -> 47616
#define OFF_GUARD 47616    // 128 B zero tail (sP row-47 overread guard)
#define SMEM_TOTAL 47744   // 46.6 KB -> 3 blocks/CU

#define MFMA16(A,B,C) __builtin_amdgcn_mfma_f32_16x16x32_bf16(A, B, C, 0, 0, 0)

__device__ __forceinline__ float dpp_add16(float v) {
    int x = __builtin_bit_cast(int, v);
    v += __builtin_bit_cast(float, __builtin_amdgcn_update_dpp(0, x, 0xB1, 0xF, 0xF, true));
    x = __builtin_bit_cast(int, v);
    v += __builtin_bit_cast(float, __builtin_amdgcn_update_dpp(0, x, 0x4E, 0xF, 0xF, true));
    x = __builtin_bit_cast(int, v);
    v += __builtin_bit_cast(float, __builtin_amdgcn_update_dpp(0, x, 0x141, 0xF, 0xF, true));
    x = __builtin_bit_cast(int, v);
    v += __builtin_bit_cast(float, __builtin_amdgcn_update_dpp(0, x, 0x140, 0xF, 0xF, true));
    return v;
}

__device__ __forceinline__ float lrelu(float t) { return t > 0.f ? t : 0.1f * t; }

// ---- prep: captions fp32 -> bf16 cache + per-caption-row L2 norms ----
__global__ __launch_bounds__(256)
void prep_kernel(const float* __restrict__ captions, bf16* __restrict__ capb,
                 float* __restrict__ w1g)
{
    const int c = blockIdx.x >> 2, q = blockIdx.x & 3;
    const int wave = threadIdx.x >> 6, lane = threadIdx.x & 63;
    #pragma unroll
    for (int j = 0; j < 3; ++j) {
        int w = q * 12 + wave * 3 + j;
        size_t off = ((size_t)c * NW + w) * ND + lane * 4;
        float4 v = *(const float4*)(captions + off);
        bf16x4 h = { (bf16)v.x, (bf16)v.y, (bf16)v.z, (bf16)v.w };
        *(bf16x4*)(capb + off) = h;
        float s = v.x*v.x + v.y*v.y + v.z*v.z + v.w*v.w;
        s += __shfl_xor(s, 1);  s += __shfl_xor(s, 2);  s += __shfl_xor(s, 4);
        s += __shfl_xor(s, 8);  s += __shfl_xor(s, 16); s += __shfl_xor(s, 32);
        if (lane == 0) w1g[c * NW + w] = sqrtf(s);
    }
}

__device__ __forceinline__ bf16x8 ld_cvt_f32(const float* p, float& ss) {
    float4 lo = *(const float4*)p;
    float4 hi = *(const float4*)(p + 4);
    ss += lo.x*lo.x + lo.y*lo.y + lo.z*lo.z + lo.w*lo.w
        + hi.x*hi.x + hi.y*hi.y + hi.z*hi.z + hi.w*hi.w;
    bf16x8 r = { (bf16)lo.x, (bf16)lo.y, (bf16)lo.z, (bf16)lo.w,
                 (bf16)hi.x, (bf16)hi.y, (bf16)hi.z, (bf16)hi.w };
    return r;
}

template<bool USE_WS>
__global__ __launch_bounds__(256, 3)   // 3 blocks/CU; VGPR cap ~170, demand ~140
void scan_main(const float* __restrict__ images,
               const float* __restrict__ captions,
               const bf16* __restrict__ capb,
               const float* __restrict__ w1g,
               float* __restrict__ out)
{
    __shared__ __align__(16) unsigned char smem[SMEM_TOTAL];
    bf16* sIb = (bf16*)(smem + OFF_IB);   // [r][d] image, rows 36..47 zeroed
    bf16* sG  = (bf16*)(smem + OFF_G);    // [r'][r] Gram, rows/cols >=36 clean zeros

    const int tid  = threadIdx.x;
    const int wave = tid >> 6;
    const int lane = tid & 63;
    const int quad = lane >> 4;
    const int l15  = lane & 15;
    const int i    = blockIdx.x >> 3;
    const int c0   = (blockIdx.x & 7) * 32;   // chunk == blockIdx%8 -> XCD-pinned captions

    bf16* sPw = (bf16*)(smem + OFF_P) + wave * (48 * PSP);

    // ---- init: stage image bf16, zero pads / sG / sP+guard ----
    const float* gI = images + (size_t)i * NR * ND;
    #pragma unroll
    for (int k = 0; k < 9; ++k) {
        int t = tid + k * 256;               // 2304 float4
        int e = t * 4, r = e >> 8, d = e & 255;
        float4 v = *(const float4*)(gI + e);
        bf16x4 h = { (bf16)v.x, (bf16)v.y, (bf16)v.z, (bf16)v.w };
        *(bf16x4*)&sIb[r * PIB + d] = h;
    }
    {
        uint32_t* pIb = (uint32_t*)sIb;      // rows 36..47 -> 0 (dwords 4752..6335)
        #pragma unroll
        for (int k = 0; k < 7; ++k) { int x = tid + k * 256; if (x < 1584) pIb[4752 + x] = 0u; }
        uint32_t* pG = (uint32_t*)sG;        // whole sG (1728 dwords)
        #pragma unroll
        for (int k = 0; k < 7; ++k) { int x = tid + k * 256; if (x < 1728) pG[x] = 0u; }
        uint32_t* pP = (uint32_t*)(smem + OFF_P);   // whole sP region + guard (3872 dwords)
        #pragma unroll
        for (int k = 0; k < 16; ++k) { int x = tid + k * 256; if (x < 3872) pP[x] = 0u; }
    }
    __syncthreads();   // B0

    // ---- once: Gram G = I*I^T (waves 0-2); pads become clean zeros ----
    if (wave < 3) {
        f32x4 g0 = {0,0,0,0}, g1 = {0,0,0,0}, g2 = {0,0,0,0};
        #pragma unroll
        for (int ks = 0; ks < 8; ++ks) {
            bf16x8 a  = *(const bf16x8*)&sIb[(wave * 16 + l15) * PIB + ks * 32 + quad * 8];
            bf16x8 b0 = *(const bf16x8*)&sIb[(l15)      * PIB + ks * 32 + quad * 8];
            bf16x8 b1 = *(const bf16x8*)&sIb[(16 + l15) * PIB + ks * 32 + quad * 8];
            bf16x8 b2 = *(const bf16x8*)&sIb[(32 + l15) * PIB + ks * 32 + quad * 8];
            g0 = MFMA16(a, b0, g0); g1 = MFMA16(a, b1, g1); g2 = MFMA16(a, b2, g2);
        }
        #pragma unroll
        for (int p = 0; p < 4; ++p) {
            int m = wave * 16 + quad * 4 + p;
            sG[m * PG + l15]      = (bf16)g0[p];
            sG[m * PG + 16 + l15] = (bf16)g1[p];
            sG[m * PG + 32 + l15] = (bf16)g2[p];
        }
    }
    __syncthreads();   // B1: sG published. No further barriers — waves fully independent.

    // ---- hoisted loop-invariant phase-2 B-fragments (Gram) ----
    bf16x8 bg0[3], bg1[3];
    #pragma unroll
    for (int nt = 0; nt < 3; ++nt) {
        bg0[nt] = *(const bf16x8*)&sG[(nt * 16 + l15) * PG + quad * 8];
        bg1[nt] = *(const bf16x8*)&sG[(nt * 16 + l15) * PG + 32 + quad * 8];
    }

    // ---- per-wave: 8 captions, everything in-wave ----
    for (int it = 0; it < 8; ++it) {
        const int c = c0 + wave * 8 + it;

        float w1v[3][4];
        if (USE_WS) {
            #pragma unroll
            for (int mt = 0; mt < 3; ++mt)
                #pragma unroll
                for (int p = 0; p < 4; ++p)
                    w1v[mt][p] = w1g[(size_t)c * NW + mt * 16 + quad * 4 + p];
        }

        // ---- phase 1: raw logits attnT[w][r] = C_c · I^T (acc = pre-leaky raw) ----
        f32x4 acc[3][3] = {};
        float ssc[3] = {0.f, 0.f, 0.f};
        const bf16*  ab   = USE_WS ? capb + ((size_t)c * NW + l15) * ND + quad * 8 : nullptr;
        const float* ab32 = USE_WS ? nullptr : captions + ((size_t)c * NW + l15) * ND + quad * 8;
        #pragma unroll
        for (int ks = 0; ks < 8; ++ks) {
            bf16x8 a0, a1, a2;
            if (USE_WS) {
                a0 = *(const bf16x8*)(ab + ks * 32);
                a1 = *(const bf16x8*)(ab + 16 * ND + ks * 32);
                a2 = *(const bf16x8*)(ab + 32 * ND + ks * 32);
            } else {
                a0 = ld_cvt_f32(ab32 + ks * 32, ssc[0]);
                a1 = ld_cvt_f32(ab32 + 16 * ND + ks * 32, ssc[1]);
                a2 = ld_cvt_f32(ab32 + 32 * ND + ks * 32, ssc[2]);
            }
            bf16x8 b0 = *(const bf16x8*)&sIb[(l15)      * PIB + ks * 32 + quad * 8];
            bf16x8 b1 = *(const bf16x8*)&sIb[(16 + l15) * PIB + ks * 32 + quad * 8];
            bf16x8 b2 = *(const bf16x8*)&sIb[(32 + l15) * PIB + ks * 32 + quad * 8];
            acc[0][0] = MFMA16(a0, b0, acc[0][0]);
            acc[1][0] = MFMA16(a1, b0, acc[1][0]);
            acc[2][0] = MFMA16(a2, b0, acc[2][0]);
            acc[0][1] = MFMA16(a0, b1, acc[0][1]);
            acc[1][1] = MFMA16(a1, b1, acc[1][1]);
            acc[2][1] = MFMA16(a2, b1, acc[2][1]);
            acc[0][2] = MFMA16(a0, b2, acc[0][2]);
            acc[1][2] = MFMA16(a1, b2, acc[1][2]);
            acc[2][2] = MFMA16(a2, b2, acc[2][2]);
        }
        if (!USE_WS) {
            #pragma unroll
            for (int mt = 0; mt < 3; ++mt) {
                float s = ssc[mt];
                s += __shfl_xor(s, 16); s += __shfl_xor(s, 32);
                ssc[mt] = sqrtf(s);
            }
            #pragma unroll
            for (int mt = 0; mt < 3; ++mt)
                #pragma unroll
                for (int p = 0; p < 4; ++p)
                    w1v[mt][p] = __shfl(ssc[mt], (lane & 48) + quad * 4 + p);
        }

        // ---- l2norm over w (leaky applied on the fly); fold 9*log2e into inv ----
        float inv[3];
        #pragma unroll
        for (int nt = 0; nt < 3; ++nt) {
            float s = 0.f;
            #pragma unroll
            for (int mt = 0; mt < 3; ++mt)
                #pragma unroll
                for (int p = 0; p < 4; ++p) { float t = lrelu(acc[mt][nt][p]); s += t * t; }
            s += __shfl_xor(s, 16); s += __shfl_xor(s, 32);       // sum over w-quads
            inv[nt] = SOFT_SCALE / (sqrtf(s) + 1e-8f);
        }

        // ---- un-normalized softmax: e = exp2(leaky*inv). No max-sub (|9*xhat|<=9),
        //      no sum-normalization (1/s cancels in rsim). w12' = sum_r e*raw. ----
        float q[3][3][4];                    // un-normalized e, C-layout
        float w12v[3][4];                    // un-normalized numerator
        #pragma unroll
        for (int mt = 0; mt < 3; ++mt) {
            #pragma unroll
            for (int p = 0; p < 4; ++p) {
                float e0 = exp2f(lrelu(acc[mt][0][p]) * inv[0]);
                float e1 = exp2f(lrelu(acc[mt][1][p]) * inv[1]);
                float e2 = (l15 < 4) ? exp2f(lrelu(acc[mt][2][p]) * inv[2]) : 0.f;  // mask r>=36
                w12v[mt][p] = dpp_add16(e0 * acc[mt][0][p] + e1 * acc[mt][1][p]
                                       + e2 * acc[mt][2][p]);
                q[mt][0][p] = e0; q[mt][1][p] = e1; q[mt][2][p] = e2;
                int row = mt * 16 + quad * 4 + p;
                sPw[row * PSP + l15]      = (bf16)e0;
                sPw[row * PSP + 16 + l15] = (bf16)e1;
                if (l15 < 4) sPw[row * PSP + 32 + l15] = (bf16)e2;   // cols 36..39 stay 0
            }
        }
        // same-wave RAW on sPw -> compiler inserts lgkmcnt; no barrier

        // ---- phase 2: eG = e·G (K=64; k>=36 contributions provably 0) ----
        f32x4 pg[3][3] = {};
        #pragma unroll
        for (int mt = 0; mt < 3; ++mt) {
            const bf16* ap = &sPw[(mt * 16 + l15) * PSP];
            bf16x8 pa0 = *(const bf16x8*)(ap + quad * 8);
            bf16x8 pa1 = *(const bf16x8*)(ap + 32 + quad * 8);   // overreads: finite x sG-zeros
            #pragma unroll
            for (int nt = 0; nt < 3; ++nt) {
                pg[mt][nt] = MFMA16(pa0, bg0[nt], pg[mt][nt]);
                pg[mt][nt] = MFMA16(pa1, bg1[nt], pg[mt][nt]);
            }
        }

        // ---- w2' = e^T G e; rsim = w12'/(w1*sqrt(w2')); LSE (no max-sub, |lv|<=6) ----
        float esum = 0.f;
        #pragma unroll
        for (int mt = 0; mt < 3; ++mt) {
            #pragma unroll
            for (int p = 0; p < 4; ++p) {
                float s2 = pg[mt][0][p] * q[mt][0][p]
                         + pg[mt][1][p] * q[mt][1][p]
                         + pg[mt][2][p] * q[mt][2][p];
                s2 = dpp_add16(s2);
                float w2v = sqrtf(fmaxf(s2, 0.f));
                float rsim = w12v[mt][p] / fmaxf(w1v[mt][p] * w2v, 1e-8f);
                esum += __expf(6.0f * rsim);
            }
        }
        esum += __shfl_xor(esum, 16); esum += __shfl_xor(esum, 32);
        if (lane == 0) out[(size_t)i * NC + c] = logf(esum) * (1.0f / 6.0f);
    }
}

extern "C" void kernel_launch(void* const* d_in, const int* in_sizes, int n_in,
                              void* d_out, int out_size, void* d_ws, size_t ws_size,
                              hipStream_t stream) {
    const float* images   = (const float*)d_in[0];   // (128, 36, 256) fp32
    const float* captions = (const float*)d_in[1];   // (256, 48, 256) fp32
    float* out = (float*)d_out;                      // (128, 256) fp32

    const size_t need_w1  = (size_t)NC * NW * sizeof(float);   // 49152
    const size_t need_cap = (size_t)NC * NW * ND * 2;          // 6291456
    bool use_ws = ws_size >= need_w1 + need_cap;

    dim3 grid(1024), block(256);
    if (use_ws) {
        float* w1g = (float*)d_ws;
        bf16*  capb = (bf16*)((char*)d_ws + need_w1);
        hipLaunchKernelGGL(prep_kernel, dim3(1024), dim3(256), 0, stream, captions, capb, w1g);
        hipLaunchKernelGGL((scan_main<true>), grid, block, 0, stream, images, captions, capb, w1g, out);
    } else {
        hipLaunchKernelGGL((scan_main<false>), grid, block, 0, stream, images, captions,
                           (const bf16*)nullptr, (const float*)nullptr, out);
    }
}